// Round 5
// baseline (285.244 us; speedup 1.0000x reference)
//
#include <hip/hip_runtime.h>
#include <hip/hip_bf16.h>
#include <stdint.h>
#include <stddef.h>

#define B_ 4
#define S_ 2048
#define D_ 1024
#define H_ 16
#define HD_ 64
#define NTOK (B_*S_)      // 8192
#define HDIM (H_*HD_)     // 1024
#define LOG2E 1.44269504088896f

typedef __bf16 bf16_t;
typedef __bf16 bf16x4 __attribute__((ext_vector_type(4)));
typedef __bf16 bf16x8 __attribute__((ext_vector_type(8)));
typedef float floatx4 __attribute__((ext_vector_type(4)));

#define MFMA16(a,b,c)  __builtin_amdgcn_mfma_f32_16x16x32_bf16((a),(b),(c),0,0,0)

// async global->LDS, 16 B per lane; LDS dst must be wave-uniform-base + lane*16
__device__ __forceinline__ void async_cp16(const bf16_t* g, bf16_t* l) {
    typedef __attribute__((address_space(1))) const unsigned int gu32;
    typedef __attribute__((address_space(3))) unsigned int lu32;
    __builtin_amdgcn_global_load_lds((gu32*)g, (lu32*)l, 16, 0, 0);
}

__device__ __forceinline__ bf16x8 cat44(bf16x4 a, bf16x4 b) {
    union { bf16x4 h[2]; bf16x8 v; } u;
    u.h[0] = a; u.h[1] = b;
    return u.v;
}

// ------- fp32 -> bf16 bulk convert (5 segments) + cos/sin pack (z=5) -------
// z=5 builds cpk[token][l16][j][(cos,sin)] f32: the pair for true d = j*16+l16
// lands at f32 offset bs*128 + l16*8 + j*2, so the gemm1 epilogue fetches all
// four pairs for its lane with TWO float4 loads. cpk lives in d_out scratch
// (overwritten by gemm2 at the end) -> ZERO workspace growth.
struct Cvt6 {
    const float* s[5]; bf16_t* d[5]; int n4[5];
    const float* cs; const float* sn; float* cpk;
};

__global__ __launch_bounds__(256) void cvt6(Cvt6 p) {
    const int z = blockIdx.y;
    if (z < 5) {
        const float4* __restrict__ src = (const float4*)p.s[z];
        bf16x4* __restrict__ dst = (bf16x4*)p.d[z];
        const int n4 = p.n4[z];
        for (int i = blockIdx.x * 256 + threadIdx.x; i < n4; i += gridDim.x * 256) {
            const float4 v = src[i];
            dst[i] = (bf16x4){(bf16_t)v.x, (bf16_t)v.y, (bf16_t)v.z, (bf16_t)v.w};
        }
    } else {
        const int N = B_*S_*HD_;
        for (int i = blockIdx.x * 256 + threadIdx.x; i < N; i += gridDim.x * 256) {
            const int bs = i >> 6, d = i & 63;
            float2 cs2;
            cs2.x = p.cs[i];
            cs2.y = p.sn[i];
            *(float2*)(p.cpk + (size_t)bs*128 + (d & 15)*8 + (d >> 4)*2) = cs2;
        }
    }
}

// ---------------- NT GEMM, BK=64 (dual stride-32 buffers) -----------------
// MODE 1 (QKV projection) fuses the entire norm_rope pass into the epilogue:
// each wave's acc tile is 64 rows x 64 cols = 64 tokens x ONE head (wn picks
// the head), so RMS over d is Sum_j acc^2 + 4x shfl_xor over l16, RoPE's
// partner d^16 is the SAME LANE at j^1 (zero cross-lane), and V (z=2) is
// normed + transposed to vt[bh][d][s] through the dead LDS (per-wave scratch,
// two 32-d passes, stride 72 els so b128 reads stay 16B-aligned).
// cos/sin come from the cpk packed table (two float4 loads per token-row)
// -- value-identical to the verified scalar-load epilogue, positions and
// stores unchanged.
struct GemmPtrs {
    const bf16_t* A[3]; const bf16_t* W[3]; void* C[3];
    const float* cpk; const float* qs; const float* ks;
};

template<int MODE>
__global__ __launch_bounds__(256, 3) void gemm_nt(GemmPtrs p, int K) {
    __shared__ bf16_t lds[4*4096];       // 32 KB: lA0|lA1|lB0|lB1
    bf16_t* lA0 = lds;
    bf16_t* lA1 = lds + 4096;
    bf16_t* lB0 = lds + 8192;
    bf16_t* lB1 = lds + 12288;
    const bf16_t* __restrict__ A = p.A[blockIdx.z];
    const bf16_t* __restrict__ W = p.W[blockIdx.z];
    const int m0 = blockIdx.y * 128;
    const int n0 = blockIdx.x * 128;
    const int t = threadIdx.x;
    const int lane = t & 63;
    const int wave = t >> 6;
    const int wm = wave >> 1;
    const int wn = wave & 1;
    const int l16 = lane & 15;
    const int quad = lane >> 4;

    const int srow0 = wave*32 + (lane >> 2);
    const int skc   = (lane & 3) * 8;

    floatx4 acc[4][4] = {};

    for (int k0 = 0; k0 < K; k0 += 64) {
        #pragma unroll
        for (int c = 0; c < 2; ++c) {
            const int row = srow0 + c*16;
            const size_t ao = (size_t)(m0+row)*K + k0 + skc;
            const size_t wo = (size_t)(n0+row)*K + k0 + skc;
            async_cp16(&A[ao],      &lA0[row*32 + skc]);
            async_cp16(&A[ao + 32], &lA1[row*32 + skc]);
            async_cp16(&W[wo],      &lB0[row*32 + skc]);
            async_cp16(&W[wo + 32], &lB1[row*32 + skc]);
        }
        __syncthreads();
        {
            bf16x8 af[4], bfr[4];
            #pragma unroll
            for (int i = 0; i < 4; ++i) {
                af[i]  = *(const bf16x8*)(&lA0[(wm*64 + i*16 + l16)*32 + quad*8]);
                bfr[i] = *(const bf16x8*)(&lB0[(wn*64 + i*16 + l16)*32 + quad*8]);
            }
            #pragma unroll
            for (int i = 0; i < 4; ++i)
                #pragma unroll
                for (int j = 0; j < 4; ++j)
                    acc[i][j] = MFMA16(af[i], bfr[j], acc[i][j]);
        }
        {
            bf16x8 af[4], bfr[4];
            #pragma unroll
            for (int i = 0; i < 4; ++i) {
                af[i]  = *(const bf16x8*)(&lA1[(wm*64 + i*16 + l16)*32 + quad*8]);
                bfr[i] = *(const bf16x8*)(&lB1[(wn*64 + i*16 + l16)*32 + quad*8]);
            }
            #pragma unroll
            for (int i = 0; i < 4; ++i)
                #pragma unroll
                for (int j = 0; j < 4; ++j)
                    acc[i][j] = MFMA16(af[i], bfr[j], acc[i][j]);
        }
        __syncthreads();
    }

    if (MODE == 1) {
        // ---- fused RMSNorm (+RoPE for q,k / +transpose for v) epilogue ----
        const int z = blockIdx.z;
        const int h = blockIdx.x*2 + wn;          // head index 0..15
        // inv_rms per row (i,r): mean over the 64 d of this head
        float inv[4][4];
        #pragma unroll
        for (int i = 0; i < 4; ++i) {
            #pragma unroll
            for (int r = 0; r < 4; ++r) {
                float ssq = 0.f;
                #pragma unroll
                for (int j = 0; j < 4; ++j) ssq += acc[i][j][r]*acc[i][j][r];
                ssq += __shfl_xor(ssq, 1);
                ssq += __shfl_xor(ssq, 2);
                ssq += __shfl_xor(ssq, 4);
                ssq += __shfl_xor(ssq, 8);
                inv[i][r] = rsqrtf(ssq*(1.f/64.f) + 1e-6f);
            }
        }
        if (z < 2) {
            bf16_t* __restrict__ C = (bf16_t*)p.C[z];
            const float* __restrict__ scp = (z == 0) ? p.qs : p.ks;
            const float scl = (z == 0) ? LOG2E : 1.f;   // fold exp2 scale into q
            float qsl[4];
            #pragma unroll
            for (int j = 0; j < 4; ++j) qsl[j] = scp[j*16 + l16] * scl;
            #pragma unroll
            for (int i = 0; i < 4; ++i) {
                #pragma unroll
                for (int r = 0; r < 4; ++r) {
                    const int m = m0 + wm*64 + i*16 + quad*4 + r;
                    const int b = m >> 11, s = m & (S_-1);
                    float nv[4];
                    #pragma unroll
                    for (int j = 0; j < 4; ++j) nv[j] = acc[i][j][r] * inv[i][r] * qsl[j];
                    // cpk pairs: (c0,s0,c1,s1)(c2,s2,c3,s3), c_j at true d=j*16+l16
                    const float* cb = p.cpk + ((size_t)b*S_ + s)*128 + l16*8;
                    const float4 L0 = *(const float4*)(cb);
                    const float4 L1 = *(const float4*)(cb + 4);
                    // verified RoPE: o_j = nv[j]*c_j + sg_j*nv[j^1]*s_j,
                    // sg_j = (j&1) ? +1 : -1 (partner j^1 is same-lane)
                    bf16_t* crow = &C[(((size_t)b*H_ + h)*S_ + s)*HD_ + l16];
                    crow[0]  = (bf16_t)(nv[0]*L0.x - nv[1]*L0.y);
                    crow[16] = (bf16_t)(nv[1]*L0.z + nv[0]*L0.w);
                    crow[32] = (bf16_t)(nv[2]*L1.x - nv[3]*L1.y);
                    crow[48] = (bf16_t)(nv[3]*L1.z + nv[2]*L1.w);
                }
            }
        } else {
            // V: rms only, transpose 64x64 per wave -> vt[bh][d][s]
            bf16_t* __restrict__ Vt = (bf16_t*)p.C[2];
            const int mbase = m0 + wm*64;
            const int b = mbase >> 11;
            const int sbase = mbase & (S_-1);
            bf16_t* wl = lds + wave*2304;          // 32 x 72 els per wave
            #pragma unroll
            for (int ps = 0; ps < 2; ++ps) {       // d half-tile: d = ps*32 + dd
                #pragma unroll
                for (int jj = 0; jj < 2; ++jj) {
                    const int j = ps*2 + jj;
                    const int dd = jj*16 + l16;    // 0..31
                    #pragma unroll
                    for (int i = 0; i < 4; ++i) {
                        bf16x4 pk;
                        #pragma unroll
                        for (int r = 0; r < 4; ++r)
                            pk[r] = (bf16_t)(acc[i][j][r] * inv[i][r]);
                        *(bf16x4*)(&wl[dd*72 + i*16 + quad*4]) = pk;
                    }
                }
                // read transposed: lane -> d row (lane>>1), k half (lane&1)*32
                const int dloc = lane >> 1;
                const int kh = (lane & 1) * 32;
                bf16_t* dst = &Vt[((size_t)(b*H_ + h)*HD_ + ps*32 + dloc)*S_ + sbase + kh];
                #pragma unroll
                for (int c = 0; c < 4; ++c) {
                    const bf16x8 vv = *(const bf16x8*)(&wl[dloc*72 + kh + c*8]);
                    *(bf16x8*)(&dst[c*8]) = vv;
                }
            }
        }
    } else {
        float* __restrict__ C = (float*)p.C[blockIdx.z];
        #pragma unroll
        for (int i = 0; i < 4; ++i) {
            const int mb = m0 + wm*64 + i*16 + quad*4;
            #pragma unroll
            for (int j = 0; j < 4; ++j) {
                const int n = n0 + wn*64 + j*16 + l16;
                #pragma unroll
                for (int r = 0; r < 4; ++r)
                    C[(size_t)(mb + r)*HDIM + n] = acc[i][j][r];
            }
        }
    }
}

// ---------------- flash attention v6 ---------------------------------------
// S^T trick: S^T = K Q^T so exp2'd C-layout output stays in registers.
// PV at K=32 full rate via kappa k-permutation (identical in both operands is
// algebra-neutral); V^T staged in LDS in kappa order. Fragment-linear LDS
// layouts -> all ds_reads wave-contiguous b128; K staged via global_load_lds.
__global__ __launch_bounds__(512, 4) void flash_attn(
    const bf16_t* __restrict__ qn, const bf16_t* __restrict__ kn,
    const bf16_t* __restrict__ vt, bf16_t* __restrict__ attn_out) {
    // sh: [0,4096)=Kbuf0 [4096,8192)=Kbuf1 [8192,12288)=Vbuf0 [12288,16384)=Vbuf1
    __shared__ __align__(16) bf16_t sh[16384];   // 32 KB

    const int bh = blockIdx.y;
    const int b  = bh >> 4;
    const int h  = bh & 15;
    const int q0 = blockIdx.x * 256;
    const int t = threadIdx.x;
    const int wave = t >> 6;
    const int lane = t & 63;
    const int l16 = lane & 15;
    const int quad = lane >> 4;
    const floatx4 finit = {-46.f, -46.f, -46.f, -46.f};

    const bf16_t* Q  = qn + (size_t)bh * S_ * HD_;
    const bf16_t* K  = kn + (size_t)bh * S_ * HD_;
    const bf16_t* Vt = vt + (size_t)bh * HD_ * S_;

    // Q fragments (B-operand of S^T): n=q=l16, k=d=quad*8+j
    bf16x8 qf[2][2];
    #pragma unroll
    for (int rb = 0; rb < 2; ++rb) {
        const int qrow = q0 + wave*32 + rb*16 + l16;
        qf[rb][0] = *(const bf16x8*)(&Q[(size_t)qrow*HD_ + quad*8]);
        qf[rb][1] = *(const bf16x8*)(&Q[(size_t)qrow*HD_ + 32 + quad*8]);
    }

    floatx4 accO[2][4] = {};   // O^T per dt: col=q=l16, row=d_local=quad*4+reg
    float accL[2] = {0.f, 0.f};

    // staging map: thread covers global row sgrow, 8 cols at sgcol
    const int sgrow = (wave & 3)*16 + l16;
    const int sgcol = (wave >> 2)*32 + quad*8;
    const int kwoff = (wave & 3)*1024 + (wave >> 2)*512 + lane*8;
    const int vU    = ((wave & 3)*2 + (wave >> 2))*64 + ((2*quad) & 3)*16 + l16;
    const int vwoff = vU*8 + (quad >> 1)*4;

    async_cp16(&K[(size_t)sgrow*HD_ + sgcol], &sh[kwoff]);
    {
        const bf16x8 v0 = *(const bf16x8*)(&Vt[(size_t)sgrow*S_ + sgcol]);
        union { bf16x8 v; bf16x4 hh[2]; } uv; uv.v = v0;
        *(bf16x4*)(&sh[8192 + vwoff])       = uv.hh[0];
        *(bf16x4*)(&sh[8192 + vwoff + 128]) = uv.hh[1];
    }

    bf16x8 vpre;
    for (int i = 0; i < S_/64; ++i) {
        __syncthreads();                 // buf[i&1] staged (vmcnt+lgkm drained)
        const bf16_t* lK = sh + (i & 1)*4096;
        const bf16_t* lV = sh + 8192 + (i & 1)*4096;
        const bool more = (i + 1 < S_/64);
        if (more) {
            const int ktn = (i + 1) * 64;
            async_cp16(&K[(size_t)(ktn + sgrow)*HD_ + sgcol],
                       &sh[((i+1) & 1)*4096 + kwoff]);
            vpre = *(const bf16x8*)(&Vt[(size_t)sgrow*S_ + ktn + sgcol]);
        }

        __builtin_amdgcn_s_setprio(1);
        // S^T = K Q^T - 46 ; P^T = exp2 (C-layout: k=ct*16+quad*4+r, q=l16)
        bf16x4 pf[2][4];
        #pragma unroll
        for (int ct = 0; ct < 4; ++ct) {
            const bf16x8 kf0 = *(const bf16x8*)(&lK[ct*1024 + lane*8]);
            const bf16x8 kf1 = *(const bf16x8*)(&lK[ct*1024 + 512 + lane*8]);
            #pragma unroll
            for (int rb = 0; rb < 2; ++rb) {
                floatx4 s = MFMA16(kf0, qf[rb][0], finit);
                s = MFMA16(kf1, qf[rb][1], s);
                const float e0 = __builtin_amdgcn_exp2f(s[0]);
                const float e1 = __builtin_amdgcn_exp2f(s[1]);
                const float e2 = __builtin_amdgcn_exp2f(s[2]);
                const float e3 = __builtin_amdgcn_exp2f(s[3]);
                accL[rb] += (e0 + e1) + (e2 + e3);
                bf16x4 pb;
                pb[0] = (bf16_t)e0; pb[1] = (bf16_t)e1;
                pb[2] = (bf16_t)e2; pb[3] = (bf16_t)e3;
                pf[rb][ct] = pb;
            }
        }
        bf16x8 pb8[2][2];
        #pragma unroll
        for (int rb = 0; rb < 2; ++rb) {
            pb8[rb][0] = cat44(pf[rb][0], pf[rb][1]);
            pb8[rb][1] = cat44(pf[rb][2], pf[rb][3]);
        }
        // O^T += V^T P^T at K=32 (A = kappa-ordered V^T frags, contiguous b128)
        #pragma unroll
        for (int dt = 0; dt < 4; ++dt) {
            #pragma unroll
            for (int c = 0; c < 2; ++c) {
                const bf16x8 vf = *(const bf16x8*)(&lV[(dt*2 + c)*512 + lane*8]);
                accO[0][dt] = MFMA16(vf, pb8[0][c], accO[0][dt]);
                accO[1][dt] = MFMA16(vf, pb8[1][c], accO[1][dt]);
            }
        }
        __builtin_amdgcn_s_setprio(0);

        if (more) {
            bf16_t* nV = sh + 8192 + ((i+1) & 1)*4096;
            union { bf16x8 v; bf16x4 hh[2]; } uv; uv.v = vpre;
            *(bf16x4*)(&nV[vwoff])       = uv.hh[0];
            *(bf16x4*)(&nV[vwoff + 128]) = uv.hh[1];
        }
    }

    __syncthreads();   // W scratch below overlaps the live Kbuf1/Vbuf1 regions
    // epilogue: reduce L across quads, transpose O^T via sh scratch
    bf16_t* W = sh + wave * (16*72);
    #pragma unroll
    for (int rb = 0; rb < 2; ++rb) {
        float lr = accL[rb];
        lr += __shfl_xor(lr, 16);
        lr += __shfl_xor(lr, 32);
        const float inv = 1.f / lr;        // L[q=l16]
        #pragma unroll
        for (int dt = 0; dt < 4; ++dt)
            #pragma unroll
            for (int r = 0; r < 4; ++r)
                W[l16*72 + dt*16 + quad*4 + r] = (bf16_t)(accO[rb][dt][r] * inv);
        #pragma unroll
        for (int half = 0; half < 2; ++half) {
            const int qr = half*8 + (lane >> 3);
            const bf16x8 o = *(const bf16x8*)(&W[qr*72 + (lane & 7)*8]);
            const int srw = q0 + wave*32 + rb*16 + qr;
            *(bf16x8*)(&attn_out[((size_t)b*S_ + srw)*HDIM + h*HD_ + (lane & 7)*8]) = o;
        }
    }
}

extern "C" void kernel_launch(void* const* d_in, const int* in_sizes, int n_in,
                              void* d_out, int out_size, void* d_ws, size_t ws_size,
                              hipStream_t stream) {
    (void)in_sizes; (void)n_in; (void)out_size; (void)ws_size;
    const float* X  = (const float*)d_in[0];
    const float* cs = (const float*)d_in[1];
    const float* sn = (const float*)d_in[2];
    const float* wq = (const float*)d_in[4];
    const float* wk = (const float*)d_in[5];
    const float* wv = (const float*)d_in[6];
    const float* wo = (const float*)d_in[7];
    const float* qs = (const float*)d_in[8];
    const float* ks = (const float*)d_in[9];
    float* out = (float*)d_out;

    const size_t PROJ = (size_t)NTOK * HDIM;
    const size_t WSZ  = (size_t)HDIM * D_;
    bf16_t* ws   = (bf16_t*)d_ws;
    bf16_t* Xb   = ws;                 // dead after gemm1 -> reused as attn
    bf16_t* wqb  = ws + PROJ;
    bf16_t* wkb  = wqb + WSZ;
    bf16_t* wvb  = wkb + WSZ;
    bf16_t* wob  = wvb + WSZ;
    bf16_t* qb   = wob + WSZ;
    bf16_t* kb   = qb + PROJ;
    bf16_t* vb   = kb + PROJ;          // vt lives here (written by gemm1 z=2)
    bf16_t* vt   = vb;
    bf16_t* attn = Xb;                 // total ws: 72 MB (unchanged)
    // cpk scratch lives in d_out (4 MB of 32 MB); gemm2 overwrites all of out
    float*  cpk  = out;

    Cvt6 cp;
    cp.s[0] = X;  cp.d[0] = Xb;  cp.n4[0] = (int)(PROJ/4);
    cp.s[1] = wq; cp.d[1] = wqb; cp.n4[1] = (int)(WSZ/4);
    cp.s[2] = wk; cp.d[2] = wkb; cp.n4[2] = (int)(WSZ/4);
    cp.s[3] = wv; cp.d[3] = wvb; cp.n4[3] = (int)(WSZ/4);
    cp.s[4] = wo; cp.d[4] = wob; cp.n4[4] = (int)(WSZ/4);
    cp.cs = cs; cp.sn = sn; cp.cpk = cpk;
    cvt6<<<dim3(1024, 6), 256, 0, stream>>>(cp);

    GemmPtrs g1;
    g1.A[0] = Xb;  g1.A[1] = Xb;  g1.A[2] = Xb;
    g1.W[0] = wqb; g1.W[1] = wkb; g1.W[2] = wvb;
    g1.C[0] = qb;  g1.C[1] = kb;  g1.C[2] = vt;
    g1.cpk = cpk; g1.qs = qs; g1.ks = ks;
    gemm_nt<1><<<dim3(HDIM/128, NTOK/128, 3), 256, 0, stream>>>(g1, D_);

    flash_attn<<<dim3(S_/256, B_*H_), 512, 0, stream>>>(qb, kb, vt, attn);

    GemmPtrs g2;
    g2.A[0] = attn; g2.W[0] = wob; g2.C[0] = out;
    g2.A[1] = attn; g2.W[1] = wob; g2.C[1] = out;
    g2.A[2] = attn; g2.W[2] = wob; g2.C[2] = out;
    g2.cpk = cpk; g2.qs = qs; g2.ks = ks;
    gemm_nt<2><<<dim3(HDIM/128, NTOK/128, 1), 256, 0, stream>>>(g2, HDIM);
}

// Round 6
// 258.161 us; speedup vs baseline: 1.1049x; 1.1049x over previous
//
#include <hip/hip_runtime.h>
#include <hip/hip_bf16.h>
#include <stdint.h>
#include <stddef.h>

#define B_ 4
#define S_ 2048
#define D_ 1024
#define H_ 16
#define HD_ 64
#define NTOK (B_*S_)      // 8192
#define HDIM (H_*HD_)     // 1024
#define LOG2E 1.44269504088896f

typedef __bf16 bf16_t;
typedef __bf16 bf16x4 __attribute__((ext_vector_type(4)));
typedef __bf16 bf16x8 __attribute__((ext_vector_type(8)));
typedef float floatx4 __attribute__((ext_vector_type(4)));

#define MFMA16(a,b,c)  __builtin_amdgcn_mfma_f32_16x16x32_bf16((a),(b),(c),0,0,0)

// async global->LDS, 16 B per lane; LDS dst must be wave-uniform-base + lane*16
__device__ __forceinline__ void async_cp16(const bf16_t* g, bf16_t* l) {
    typedef __attribute__((address_space(1))) const unsigned int gu32;
    typedef __attribute__((address_space(3))) unsigned int lu32;
    __builtin_amdgcn_global_load_lds((gu32*)g, (lu32*)l, 16, 0, 0);
}

__device__ __forceinline__ bf16x8 cat44(bf16x4 a, bf16x4 b) {
    union { bf16x4 h[2]; bf16x8 v; } u;
    u.h[0] = a; u.h[1] = b;
    return u.v;
}

// ------- fp32 -> bf16 bulk convert (5 segments) + cos/sin pack (z=5) -------
// z=5 builds cpk[token][l16][j][(cos,sin)] f32: the pair for true d = j*16+l16
// lands at f32 offset bs*128 + l16*8 + j*2, so the gemm1 epilogue fetches all
// four pairs for its lane with TWO float4 loads. cpk lives in d_out scratch
// (overwritten by gemm2 at the end) -> ZERO workspace growth.
struct Cvt6 {
    const float* s[5]; bf16_t* d[5]; int n4[5];
    const float* cs; const float* sn; float* cpk;
};

__global__ __launch_bounds__(256) void cvt6(Cvt6 p) {
    const int z = blockIdx.y;
    if (z < 5) {
        const float4* __restrict__ src = (const float4*)p.s[z];
        bf16x4* __restrict__ dst = (bf16x4*)p.d[z];
        const int n4 = p.n4[z];
        for (int i = blockIdx.x * 256 + threadIdx.x; i < n4; i += gridDim.x * 256) {
            const float4 v = src[i];
            dst[i] = (bf16x4){(bf16_t)v.x, (bf16_t)v.y, (bf16_t)v.z, (bf16_t)v.w};
        }
    } else {
        const int N = B_*S_*HD_;
        for (int i = blockIdx.x * 256 + threadIdx.x; i < N; i += gridDim.x * 256) {
            const int bs = i >> 6, d = i & 63;
            float2 cs2;
            cs2.x = p.cs[i];
            cs2.y = p.sn[i];
            *(float2*)(p.cpk + (size_t)bs*128 + (d & 15)*8 + (d >> 4)*2) = cs2;
        }
    }
}

// ---------------- NT GEMM, BK=64 (dual stride-32 buffers) -----------------
// MODE 1 (QKV projection) fuses the entire norm_rope pass into the epilogue
// (verified round 2/5). NEW round 6, index-only changes:
//  (T1) XCD-chunked block swizzle: lin = bx+8*by; XCD (lin&7) owns 8
//       consecutive m-panels, n fastest within -> per-XCD working set
//       (A 2MB + W 2MB) fits the 4MB L2; kills the 8x A re-fetch.
//  (T2) staging XOR swizzle, both-sides-or-neither (rule 21): LDS dest
//       linear (global_load_lds legal), global SOURCE col ^ gsw(row),
//       reads ^ glw(l16) — same involution (rows are base+l16, base%16==0).
//       8-way bank conflict on ds_read_b128 -> 2-way (free, m136).
struct GemmPtrs {
    const bf16_t* A[3]; const bf16_t* W[3]; void* C[3];
    const float* cpk; const float* qs; const float* ks;
};

template<int MODE>
__global__ __launch_bounds__(256, 3) void gemm_nt(GemmPtrs p, int K) {
    __shared__ bf16_t lds[4*4096];       // 32 KB: lA0|lA1|lB0|lB1
    bf16_t* lA0 = lds;
    bf16_t* lA1 = lds + 4096;
    bf16_t* lB0 = lds + 8192;
    bf16_t* lB1 = lds + 12288;
    const bf16_t* __restrict__ A = p.A[blockIdx.z];
    const bf16_t* __restrict__ W = p.W[blockIdx.z];
    // T1: XCD-chunked swizzle (gridDim.x == 8; 512 blocks per z, 512%8==0)
    const int lin  = blockIdx.x + 8*blockIdx.y;
    const int slot = lin >> 3;
    const int mblk = (lin & 7)*8 + (slot >> 3);
    const int nblk = slot & 7;
    const int m0 = mblk * 128;
    const int n0 = nblk * 128;
    const int t = threadIdx.x;
    const int lane = t & 63;
    const int wave = t >> 6;
    const int wm = wave >> 1;
    const int wn = wave & 1;
    const int l16 = lane & 15;
    const int quad = lane >> 4;

    const int srow0 = wave*32 + (lane >> 2);
    const int skc   = (lane & 3) * 8;
    // T2: source-column XOR for the staged row (same for c=0,1: +16 keeps g)
    const int gsw   = ((srow0 ^ (srow0 >> 2)) & 3) * 8;
    // read-side XOR (row = 16*base + l16 -> g depends only on l16)
    const int glw   = ((l16 ^ (l16 >> 2)) & 3) * 8;

    floatx4 acc[4][4] = {};

    for (int k0 = 0; k0 < K; k0 += 64) {
        #pragma unroll
        for (int c = 0; c < 2; ++c) {
            const int row = srow0 + c*16;
            const size_t ao = (size_t)(m0+row)*K + k0 + (skc ^ gsw);
            const size_t wo = (size_t)(n0+row)*K + k0 + (skc ^ gsw);
            async_cp16(&A[ao],      &lA0[row*32 + skc]);
            async_cp16(&A[ao + 32], &lA1[row*32 + skc]);
            async_cp16(&W[wo],      &lB0[row*32 + skc]);
            async_cp16(&W[wo + 32], &lB1[row*32 + skc]);
        }
        __syncthreads();
        {
            bf16x8 af[4], bfr[4];
            #pragma unroll
            for (int i = 0; i < 4; ++i) {
                af[i]  = *(const bf16x8*)(&lA0[(wm*64 + i*16 + l16)*32 + (quad*8 ^ glw)]);
                bfr[i] = *(const bf16x8*)(&lB0[(wn*64 + i*16 + l16)*32 + (quad*8 ^ glw)]);
            }
            #pragma unroll
            for (int i = 0; i < 4; ++i)
                #pragma unroll
                for (int j = 0; j < 4; ++j)
                    acc[i][j] = MFMA16(af[i], bfr[j], acc[i][j]);
        }
        {
            bf16x8 af[4], bfr[4];
            #pragma unroll
            for (int i = 0; i < 4; ++i) {
                af[i]  = *(const bf16x8*)(&lA1[(wm*64 + i*16 + l16)*32 + (quad*8 ^ glw)]);
                bfr[i] = *(const bf16x8*)(&lB1[(wn*64 + i*16 + l16)*32 + (quad*8 ^ glw)]);
            }
            #pragma unroll
            for (int i = 0; i < 4; ++i)
                #pragma unroll
                for (int j = 0; j < 4; ++j)
                    acc[i][j] = MFMA16(af[i], bfr[j], acc[i][j]);
        }
        __syncthreads();
    }

    if (MODE == 1) {
        // ---- fused RMSNorm (+RoPE for q,k / +transpose for v) epilogue ----
        const int z = blockIdx.z;
        const int h = nblk*2 + wn;                // head index 0..15
        // inv_rms per row (i,r): mean over the 64 d of this head
        float inv[4][4];
        #pragma unroll
        for (int i = 0; i < 4; ++i) {
            #pragma unroll
            for (int r = 0; r < 4; ++r) {
                float ssq = 0.f;
                #pragma unroll
                for (int j = 0; j < 4; ++j) ssq += acc[i][j][r]*acc[i][j][r];
                ssq += __shfl_xor(ssq, 1);
                ssq += __shfl_xor(ssq, 2);
                ssq += __shfl_xor(ssq, 4);
                ssq += __shfl_xor(ssq, 8);
                inv[i][r] = rsqrtf(ssq*(1.f/64.f) + 1e-6f);
            }
        }
        if (z < 2) {
            bf16_t* __restrict__ C = (bf16_t*)p.C[z];
            const float* __restrict__ scp = (z == 0) ? p.qs : p.ks;
            const float scl = (z == 0) ? LOG2E : 1.f;   // fold exp2 scale into q
            float qsl[4];
            #pragma unroll
            for (int j = 0; j < 4; ++j) qsl[j] = scp[j*16 + l16] * scl;
            #pragma unroll
            for (int i = 0; i < 4; ++i) {
                #pragma unroll
                for (int r = 0; r < 4; ++r) {
                    const int m = m0 + wm*64 + i*16 + quad*4 + r;
                    const int b = m >> 11, s = m & (S_-1);
                    float nv[4];
                    #pragma unroll
                    for (int j = 0; j < 4; ++j) nv[j] = acc[i][j][r] * inv[i][r] * qsl[j];
                    // cpk pairs: (c0,s0,c1,s1)(c2,s2,c3,s3), c_j at true d=j*16+l16
                    const float* cb = p.cpk + ((size_t)b*S_ + s)*128 + l16*8;
                    const float4 L0 = *(const float4*)(cb);
                    const float4 L1 = *(const float4*)(cb + 4);
                    // verified RoPE: o_j = nv[j]*c_j + sg_j*nv[j^1]*s_j,
                    // sg_j = (j&1) ? +1 : -1 (partner j^1 is same-lane)
                    bf16_t* crow = &C[(((size_t)b*H_ + h)*S_ + s)*HD_ + l16];
                    crow[0]  = (bf16_t)(nv[0]*L0.x - nv[1]*L0.y);
                    crow[16] = (bf16_t)(nv[1]*L0.z + nv[0]*L0.w);
                    crow[32] = (bf16_t)(nv[2]*L1.x - nv[3]*L1.y);
                    crow[48] = (bf16_t)(nv[3]*L1.z + nv[2]*L1.w);
                }
            }
        } else {
            // V: rms only, transpose 64x64 per wave -> vt[bh][d][s]
            bf16_t* __restrict__ Vt = (bf16_t*)p.C[2];
            const int mbase = m0 + wm*64;
            const int b = mbase >> 11;
            const int sbase = mbase & (S_-1);
            bf16_t* wl = lds + wave*2304;          // 32 x 72 els per wave
            #pragma unroll
            for (int ps = 0; ps < 2; ++ps) {       // d half-tile: d = ps*32 + dd
                #pragma unroll
                for (int jj = 0; jj < 2; ++jj) {
                    const int j = ps*2 + jj;
                    const int dd = jj*16 + l16;    // 0..31
                    #pragma unroll
                    for (int i = 0; i < 4; ++i) {
                        bf16x4 pk;
                        #pragma unroll
                        for (int r = 0; r < 4; ++r)
                            pk[r] = (bf16_t)(acc[i][j][r] * inv[i][r]);
                        *(bf16x4*)(&wl[dd*72 + i*16 + quad*4]) = pk;
                    }
                }
                // read transposed: lane -> d row (lane>>1), k half (lane&1)*32
                const int dloc = lane >> 1;
                const int kh = (lane & 1) * 32;
                bf16_t* dst = &Vt[((size_t)(b*H_ + h)*HD_ + ps*32 + dloc)*S_ + sbase + kh];
                #pragma unroll
                for (int c = 0; c < 4; ++c) {
                    const bf16x8 vv = *(const bf16x8*)(&wl[dloc*72 + kh + c*8]);
                    *(bf16x8*)(&dst[c*8]) = vv;
                }
            }
        }
    } else {
        float* __restrict__ C = (float*)p.C[blockIdx.z];
        #pragma unroll
        for (int i = 0; i < 4; ++i) {
            const int mb = m0 + wm*64 + i*16 + quad*4;
            #pragma unroll
            for (int j = 0; j < 4; ++j) {
                const int n = n0 + wn*64 + j*16 + l16;
                #pragma unroll
                for (int r = 0; r < 4; ++r)
                    C[(size_t)(mb + r)*HDIM + n] = acc[i][j][r];
            }
        }
    }
}

// ---------------- flash attention v6 ---------------------------------------
// S^T trick: S^T = K Q^T so exp2'd C-layout output stays in registers.
// PV at K=32 full rate via kappa k-permutation (identical in both operands is
// algebra-neutral); V^T staged in LDS in kappa order. Fragment-linear LDS
// layouts -> all ds_reads wave-contiguous b128; K staged via global_load_lds.
// NEW round 6: T1 XCD-chunked swizzle — XCD (lin&7) owns bh in [8c,8c+8),
// its 8 q-blocks per bh run on the same XCD so K/V (512 KB/bh) stay L2-hot.
__global__ __launch_bounds__(512, 4) void flash_attn(
    const bf16_t* __restrict__ qn, const bf16_t* __restrict__ kn,
    const bf16_t* __restrict__ vt, bf16_t* __restrict__ attn_out) {
    // sh: [0,4096)=Kbuf0 [4096,8192)=Kbuf1 [8192,12288)=Vbuf0 [12288,16384)=Vbuf1
    __shared__ __align__(16) bf16_t sh[16384];   // 32 KB

    const int lin  = blockIdx.x + 8*blockIdx.y;  // gridDim.x == 8
    const int slot = lin >> 3;
    const int bh   = (lin & 7)*8 + (slot >> 3);
    const int q0   = (slot & 7) * 256;
    const int b  = bh >> 4;
    const int h  = bh & 15;
    const int t = threadIdx.x;
    const int wave = t >> 6;
    const int lane = t & 63;
    const int l16 = lane & 15;
    const int quad = lane >> 4;
    const floatx4 finit = {-46.f, -46.f, -46.f, -46.f};

    const bf16_t* Q  = qn + (size_t)bh * S_ * HD_;
    const bf16_t* K  = kn + (size_t)bh * S_ * HD_;
    const bf16_t* Vt = vt + (size_t)bh * HD_ * S_;

    // Q fragments (B-operand of S^T): n=q=l16, k=d=quad*8+j
    bf16x8 qf[2][2];
    #pragma unroll
    for (int rb = 0; rb < 2; ++rb) {
        const int qrow = q0 + wave*32 + rb*16 + l16;
        qf[rb][0] = *(const bf16x8*)(&Q[(size_t)qrow*HD_ + quad*8]);
        qf[rb][1] = *(const bf16x8*)(&Q[(size_t)qrow*HD_ + 32 + quad*8]);
    }

    floatx4 accO[2][4] = {};   // O^T per dt: col=q=l16, row=d_local=quad*4+reg
    float accL[2] = {0.f, 0.f};

    // staging map: thread covers global row sgrow, 8 cols at sgcol
    const int sgrow = (wave & 3)*16 + l16;
    const int sgcol = (wave >> 2)*32 + quad*8;
    const int kwoff = (wave & 3)*1024 + (wave >> 2)*512 + lane*8;
    const int vU    = ((wave & 3)*2 + (wave >> 2))*64 + ((2*quad) & 3)*16 + l16;
    const int vwoff = vU*8 + (quad >> 1)*4;

    async_cp16(&K[(size_t)sgrow*HD_ + sgcol], &sh[kwoff]);
    {
        const bf16x8 v0 = *(const bf16x8*)(&Vt[(size_t)sgrow*S_ + sgcol]);
        union { bf16x8 v; bf16x4 hh[2]; } uv; uv.v = v0;
        *(bf16x4*)(&sh[8192 + vwoff])       = uv.hh[0];
        *(bf16x4*)(&sh[8192 + vwoff + 128]) = uv.hh[1];
    }

    bf16x8 vpre;
    for (int i = 0; i < S_/64; ++i) {
        __syncthreads();                 // buf[i&1] staged (vmcnt+lgkm drained)
        const bf16_t* lK = sh + (i & 1)*4096;
        const bf16_t* lV = sh + 8192 + (i & 1)*4096;
        const bool more = (i + 1 < S_/64);
        if (more) {
            const int ktn = (i + 1) * 64;
            async_cp16(&K[(size_t)(ktn + sgrow)*HD_ + sgcol],
                       &sh[((i+1) & 1)*4096 + kwoff]);
            vpre = *(const bf16x8*)(&Vt[(size_t)sgrow*S_ + ktn + sgcol]);
        }

        __builtin_amdgcn_s_setprio(1);
        // S^T = K Q^T - 46 ; P^T = exp2 (C-layout: k=ct*16+quad*4+r, q=l16)
        bf16x4 pf[2][4];
        #pragma unroll
        for (int ct = 0; ct < 4; ++ct) {
            const bf16x8 kf0 = *(const bf16x8*)(&lK[ct*1024 + lane*8]);
            const bf16x8 kf1 = *(const bf16x8*)(&lK[ct*1024 + 512 + lane*8]);
            #pragma unroll
            for (int rb = 0; rb < 2; ++rb) {
                floatx4 s = MFMA16(kf0, qf[rb][0], finit);
                s = MFMA16(kf1, qf[rb][1], s);
                const float e0 = __builtin_amdgcn_exp2f(s[0]);
                const float e1 = __builtin_amdgcn_exp2f(s[1]);
                const float e2 = __builtin_amdgcn_exp2f(s[2]);
                const float e3 = __builtin_amdgcn_exp2f(s[3]);
                accL[rb] += (e0 + e1) + (e2 + e3);
                bf16x4 pb;
                pb[0] = (bf16_t)e0; pb[1] = (bf16_t)e1;
                pb[2] = (bf16_t)e2; pb[3] = (bf16_t)e3;
                pf[rb][ct] = pb;
            }
        }
        bf16x8 pb8[2][2];
        #pragma unroll
        for (int rb = 0; rb < 2; ++rb) {
            pb8[rb][0] = cat44(pf[rb][0], pf[rb][1]);
            pb8[rb][1] = cat44(pf[rb][2], pf[rb][3]);
        }
        // O^T += V^T P^T at K=32 (A = kappa-ordered V^T frags, contiguous b128)
        #pragma unroll
        for (int dt = 0; dt < 4; ++dt) {
            #pragma unroll
            for (int c = 0; c < 2; ++c) {
                const bf16x8 vf = *(const bf16x8*)(&lV[(dt*2 + c)*512 + lane*8]);
                accO[0][dt] = MFMA16(vf, pb8[0][c], accO[0][dt]);
                accO[1][dt] = MFMA16(vf, pb8[1][c], accO[1][dt]);
            }
        }
        __builtin_amdgcn_s_setprio(0);

        if (more) {
            bf16_t* nV = sh + 8192 + ((i+1) & 1)*4096;
            union { bf16x8 v; bf16x4 hh[2]; } uv; uv.v = vpre;
            *(bf16x4*)(&nV[vwoff])       = uv.hh[0];
            *(bf16x4*)(&nV[vwoff + 128]) = uv.hh[1];
        }
    }

    __syncthreads();   // W scratch below overlaps the live Kbuf1/Vbuf1 regions
    // epilogue: reduce L across quads, transpose O^T via sh scratch
    bf16_t* W = sh + wave * (16*72);
    #pragma unroll
    for (int rb = 0; rb < 2; ++rb) {
        float lr = accL[rb];
        lr += __shfl_xor(lr, 16);
        lr += __shfl_xor(lr, 32);
        const float inv = 1.f / lr;        // L[q=l16]
        #pragma unroll
        for (int dt = 0; dt < 4; ++dt)
            #pragma unroll
            for (int r = 0; r < 4; ++r)
                W[l16*72 + dt*16 + quad*4 + r] = (bf16_t)(accO[rb][dt][r] * inv);
        #pragma unroll
        for (int half = 0; half < 2; ++half) {
            const int qr = half*8 + (lane >> 3);
            const bf16x8 o = *(const bf16x8*)(&W[qr*72 + (lane & 7)*8]);
            const int srw = q0 + wave*32 + rb*16 + qr;
            *(bf16x8*)(&attn_out[((size_t)b*S_ + srw)*HDIM + h*HD_ + (lane & 7)*8]) = o;
        }
    }
}

extern "C" void kernel_launch(void* const* d_in, const int* in_sizes, int n_in,
                              void* d_out, int out_size, void* d_ws, size_t ws_size,
                              hipStream_t stream) {
    (void)in_sizes; (void)n_in; (void)out_size; (void)ws_size;
    const float* X  = (const float*)d_in[0];
    const float* cs = (const float*)d_in[1];
    const float* sn = (const float*)d_in[2];
    const float* wq = (const float*)d_in[4];
    const float* wk = (const float*)d_in[5];
    const float* wv = (const float*)d_in[6];
    const float* wo = (const float*)d_in[7];
    const float* qs = (const float*)d_in[8];
    const float* ks = (const float*)d_in[9];
    float* out = (float*)d_out;

    const size_t PROJ = (size_t)NTOK * HDIM;
    const size_t WSZ  = (size_t)HDIM * D_;
    bf16_t* ws   = (bf16_t*)d_ws;
    bf16_t* Xb   = ws;                 // dead after gemm1 -> reused as attn
    bf16_t* wqb  = ws + PROJ;
    bf16_t* wkb  = wqb + WSZ;
    bf16_t* wvb  = wkb + WSZ;
    bf16_t* wob  = wvb + WSZ;
    bf16_t* qb   = wob + WSZ;
    bf16_t* kb   = qb + PROJ;
    bf16_t* vb   = kb + PROJ;          // vt lives here (written by gemm1 z=2)
    bf16_t* vt   = vb;
    bf16_t* attn = Xb;                 // total ws: 72 MB (unchanged)
    // cpk scratch lives in d_out (4 MB of 32 MB); gemm2 overwrites all of out
    float*  cpk  = out;

    Cvt6 cp;
    cp.s[0] = X;  cp.d[0] = Xb;  cp.n4[0] = (int)(PROJ/4);
    cp.s[1] = wq; cp.d[1] = wqb; cp.n4[1] = (int)(WSZ/4);
    cp.s[2] = wk; cp.d[2] = wkb; cp.n4[2] = (int)(WSZ/4);
    cp.s[3] = wv; cp.d[3] = wvb; cp.n4[3] = (int)(WSZ/4);
    cp.s[4] = wo; cp.d[4] = wob; cp.n4[4] = (int)(WSZ/4);
    cp.cs = cs; cp.sn = sn; cp.cpk = cpk;
    cvt6<<<dim3(1024, 6), 256, 0, stream>>>(cp);

    GemmPtrs g1;
    g1.A[0] = Xb;  g1.A[1] = Xb;  g1.A[2] = Xb;
    g1.W[0] = wqb; g1.W[1] = wkb; g1.W[2] = wvb;
    g1.C[0] = qb;  g1.C[1] = kb;  g1.C[2] = vt;
    g1.cpk = cpk; g1.qs = qs; g1.ks = ks;
    gemm_nt<1><<<dim3(HDIM/128, NTOK/128, 3), 256, 0, stream>>>(g1, D_);

    flash_attn<<<dim3(S_/256, B_*H_), 512, 0, stream>>>(qb, kb, vt, attn);

    GemmPtrs g2;
    g2.A[0] = attn; g2.W[0] = wob; g2.C[0] = out;
    g2.A[1] = attn; g2.W[1] = wob; g2.C[1] = out;
    g2.A[2] = attn; g2.W[2] = wob; g2.C[2] = out;
    g2.cpk = cpk; g2.qs = qs; g2.ks = ks;
    gemm_nt<2><<<dim3(HDIM/128, NTOK/128, 1), 256, 0, stream>>>(g2, HDIM);
}